// Round 5
// baseline (26665.854 us; speedup 1.0000x reference)
//
#include <hip/hip_runtime.h>

// GCN: 3-layer graph conv, N=100000 nodes, E=3.2M edges, feats 256->256->256->64.
// R5: DIAGNOSTIC build — maximally-boring fp32 pipeline.
//  - aggregation: edge-parallel fp32 atomicAdd scatter (no CSR, no shfl, no sorting)
//  - GEMM: wave-per-row VALU fp32, reads original W[K][N] layout (no transpose, no MFMA)
//  - zero bf16 anywhere; all intermediates fp32
// Purpose: if this passes, the bug was in the CSR/wave-spmm/MFMA machinery; if it fails
// with the same ~3.4e-3, the reference itself has non-fp32 numerics to mimic.

#define FEATS 256

// ---------------- graph prep ----------------

__global__ void deg_kernel(const int* __restrict__ src, const int* __restrict__ dst,
                           unsigned* __restrict__ outd, unsigned* __restrict__ ind, int nE) {
  int i = blockIdx.x * blockDim.x + threadIdx.x;
  if (i < nE) {
    atomicAdd(&outd[src[i]], 1u);
    atomicAdd(&ind[dst[i]], 1u);
  }
}

__global__ void norm_kernel(const unsigned* __restrict__ outd, const unsigned* __restrict__ ind,
                            float* __restrict__ snorm, float* __restrict__ dnorm, int nN) {
  int i = blockIdx.x * blockDim.x + threadIdx.x;
  if (i < nN) {
    unsigned od = outd[i]; if (od < 1u) od = 1u;
    unsigned id = ind[i];  if (id < 1u) id = 1u;
    snorm[i] = 1.0f / sqrtf((float)od);
    dnorm[i] = 1.0f / sqrtf((float)id);
  }
}

// X1[n][c] = feat[n][c] * snorm[n]   (fp32)
__global__ void prescale(const float* __restrict__ feat, const float* __restrict__ snorm,
                         float* __restrict__ X1, int total4 /* nN*64 */) {
  int i4 = blockIdx.x * blockDim.x + threadIdx.x;
  if (i4 >= total4) return;
  float4 v = ((const float4*)feat)[i4];
  float s = snorm[i4 >> 6];
  v.x *= s; v.y *= s; v.z *= s; v.w *= s;
  ((float4*)X1)[i4] = v;
}

// ---------------- SpMM: edge-parallel atomic scatter ----------------

// G[dst[e]][c] += X[src[e]][c], 256 cols; thread = (edge, 4-col group)
__global__ void spmm_atomic256(const float* __restrict__ X, const int* __restrict__ src,
                               const int* __restrict__ dst, float* __restrict__ G, int nE) {
  int t = blockIdx.x * blockDim.x + threadIdx.x;
  if (t >= nE * 64) return;
  int e  = t >> 6;
  int cg = (t & 63) * 4;
  int s = src[e], d = dst[e];
  float4 v = *(const float4*)(X + (size_t)s * FEATS + cg);
  float* g = G + (size_t)d * FEATS + cg;
  atomicAdd(g + 0, v.x);
  atomicAdd(g + 1, v.y);
  atomicAdd(g + 2, v.z);
  atomicAdd(g + 3, v.w);
}

// out[dst[e]][c] += X[src[e]][c], 64 cols; thread = (edge, 4-col group)
__global__ void spmm_atomic64(const float* __restrict__ X, const int* __restrict__ src,
                              const int* __restrict__ dst, float* __restrict__ out, int nE) {
  int t = blockIdx.x * blockDim.x + threadIdx.x;
  if (t >= nE * 16) return;
  int e  = t >> 4;
  int cg = (t & 15) * 4;
  int s = src[e], d = dst[e];
  float4 v = *(const float4*)(X + (size_t)s * 64 + cg);
  float* g = out + (size_t)d * 64 + cg;
  atomicAdd(g + 0, v.x);
  atomicAdd(g + 1, v.y);
  atomicAdd(g + 2, v.z);
  atomicAdd(g + 3, v.w);
}

// out[i] *= dnorm[i >> 6]   (final dst-norm scaling of 64-dim output)
__global__ void scale_out64(float* __restrict__ out, const float* __restrict__ dnorm, int total) {
  int i = blockIdx.x * blockDim.x + threadIdx.x;
  if (i < total) out[i] *= dnorm[i >> 6];
}

// ---------------- GEMM: wave-per-row VALU fp32 ----------------
// out[r][c] = f( (dn[r] * dot(A[r][:], W[:][c])) )  with optional relu and *sn[r]
// A: [nN][256] fp32;  W: [256][N] fp32 row-major (ORIGINAL layout, no transpose)

template<int NJ, bool RELU, bool SCDN, bool SCSN>
__global__ __launch_bounds__(256)
void gemm_row(const float* __restrict__ A, const float* __restrict__ W,
              const float* __restrict__ dnorm, const float* __restrict__ snorm,
              float* __restrict__ out, int nN) {
  const int N = NJ * 64;
  int wid  = (blockIdx.x * blockDim.x + threadIdx.x) >> 6;
  int lane = threadIdx.x & 63;
  if (wid >= nN) return;
  const float* Arow = A + (size_t)wid * 256;
  float acc[NJ];
#pragma unroll
  for (int j = 0; j < NJ; ++j) acc[j] = 0.f;

#pragma unroll 4
  for (int k = 0; k < 256; ++k) {
    float a = Arow[k];
    const float* wr = W + (size_t)k * N + lane;
#pragma unroll
    for (int j = 0; j < NJ; ++j) acc[j] = fmaf(a, wr[j * 64], acc[j]);
  }

  float dn = SCDN ? dnorm[wid] : 1.f;
  float sn = SCSN ? snorm[wid] : 1.f;
  float* orow = out + (size_t)wid * N + lane;
#pragma unroll
  for (int j = 0; j < NJ; ++j) {
    float v = acc[j];
    if (SCDN) v *= dn;
    if (RELU) v = fmaxf(v, 0.f);
    if (SCSN) v *= sn;
    orow[j * 64] = v;
  }
}

// ---------------- launch ----------------

extern "C" void kernel_launch(void* const* d_in, const int* in_sizes, int n_in,
                              void* d_out, int out_size, void* d_ws, size_t ws_size,
                              hipStream_t stream) {
  const float* feat = (const float*)d_in[0];
  const int*   src  = (const int*)d_in[1];
  const int*   dst  = (const int*)d_in[2];
  const float* W0   = (const float*)d_in[3];
  const float* W1   = (const float*)d_in[4];
  const float* W2   = (const float*)d_in[5];
  const int nE = in_sizes[1];
  const int nN = in_sizes[0] / FEATS;

  char* p = (char*)d_ws;
  auto alloc = [&](size_t bytes) -> void* {
    void* r = (void*)p;
    p += (bytes + 255) & ~(size_t)255;
    return r;
  };
  unsigned* outdeg = (unsigned*)alloc((size_t)nN * 4);
  unsigned* indeg  = (unsigned*)alloc((size_t)nN * 4);
  float*    snorm  = (float*)   alloc((size_t)nN * 4);
  float*    dnorm  = (float*)   alloc((size_t)nN * 4);
  float*    X      = (float*)   alloc((size_t)nN * 256 * 4);  // X1 / F1 / F2
  float*    G      = (float*)   alloc((size_t)nN * 256 * 4);  // agg buffer; layer-3 H3 reuses

  hipMemsetAsync(outdeg, 0, (size_t)nN * 4, stream);
  hipMemsetAsync(indeg,  0, (size_t)nN * 4, stream);

  const int TB = 256;
  int gE  = (nE + TB - 1) / TB;
  int gN  = (nN + TB - 1) / TB;
  int gRow = (nN * 64 + TB - 1) / TB;     // wave per row/node
  int gAg256 = (nE * 64 + TB - 1) / TB;   // thread per (edge, 4 cols) of 256
  int gAg64  = (nE * 16 + TB - 1) / TB;   // thread per (edge, 4 cols) of 64

  deg_kernel<<<gE, TB, 0, stream>>>(src, dst, outdeg, indeg, nE);
  norm_kernel<<<gN, TB, 0, stream>>>(outdeg, indeg, snorm, dnorm, nN);

  int total4 = nN * (FEATS / 4);
  prescale<<<(total4 + TB - 1) / TB, TB, 0, stream>>>(feat, snorm, X, total4);

  // layer 1: G = seg_sum(X[src] -> dst); F1 = relu(dn*G @ W0)*sn  -> X
  hipMemsetAsync(G, 0, (size_t)nN * 256 * 4, stream);
  spmm_atomic256<<<gAg256, TB, 0, stream>>>(X, src, dst, G, nE);
  gemm_row<4, true, true, true><<<gRow, TB, 0, stream>>>(G, W0, dnorm, snorm, X, nN);

  // layer 2
  hipMemsetAsync(G, 0, (size_t)nN * 256 * 4, stream);
  spmm_atomic256<<<gAg256, TB, 0, stream>>>(X, src, dst, G, nE);
  gemm_row<4, true, true, true><<<gRow, TB, 0, stream>>>(G, W1, dnorm, snorm, X, nN);

  // layer 3: H3 = X @ W2 (no relu/scale) -> G; out = dn * seg_sum(H3[src])
  gemm_row<1, false, false, false><<<gRow, TB, 0, stream>>>(X, W2, nullptr, nullptr, G, nN);
  hipMemsetAsync(d_out, 0, (size_t)nN * 64 * 4, stream);
  spmm_atomic64<<<gAg64, TB, 0, stream>>>(G, src, dst, (float*)d_out, nE);
  scale_out64<<<(nN * 64 + TB - 1) / TB, TB, 0, stream>>>((float*)d_out, dnorm, nN * 64);
}

// Round 6
// 6641.817 us; speedup vs baseline: 4.0148x; 4.0148x over previous
//
#include <hip/hip_runtime.h>

// GCN: 3-layer graph conv, N=100000 nodes, E=3.2M edges, feats 256->256->256->64.
// R6: known-good fp32 base (R5) + ONE change: the two 256-dim aggregations use
// CSR (scan+scatter) + wave-per-node fp32 gather SpMM instead of edge atomics.
// Runtime guard: if ws_size can't fit the CSR arrays, fall back to atomic path
// (distinguishes a ws-overflow root cause from a CSR/SpMM bug).

#define FEATS 256

// ---------------- graph prep ----------------

__global__ void deg_kernel(const int* __restrict__ src, const int* __restrict__ dst,
                           unsigned* __restrict__ outd, unsigned* __restrict__ ind, int nE) {
  int i = blockIdx.x * blockDim.x + threadIdx.x;
  if (i < nE) {
    atomicAdd(&outd[src[i]], 1u);
    atomicAdd(&ind[dst[i]], 1u);
  }
}

__global__ void norm_kernel(const unsigned* __restrict__ outd, const unsigned* __restrict__ ind,
                            float* __restrict__ snorm, float* __restrict__ dnorm, int nN) {
  int i = blockIdx.x * blockDim.x + threadIdx.x;
  if (i < nN) {
    unsigned od = outd[i]; if (od < 1u) od = 1u;
    unsigned id = ind[i];  if (id < 1u) id = 1u;
    snorm[i] = 1.0f / sqrtf((float)od);
    dnorm[i] = 1.0f / sqrtf((float)id);
  }
}

// X1[n][c] = feat[n][c] * snorm[n]   (fp32)
__global__ void prescale(const float* __restrict__ feat, const float* __restrict__ snorm,
                         float* __restrict__ X1, int total4 /* nN*64 */) {
  int i4 = blockIdx.x * blockDim.x + threadIdx.x;
  if (i4 >= total4) return;
  float4 v = ((const float4*)feat)[i4];
  float s = snorm[i4 >> 6];
  v.x *= s; v.y *= s; v.z *= s; v.w *= s;
  ((float4*)X1)[i4] = v;
}

// ---------------- CSR build ----------------

__global__ void scan_blocks(const unsigned* __restrict__ in, unsigned* __restrict__ excl,
                            unsigned* __restrict__ partials, int n) {
  __shared__ unsigned tmp[1024];
  int t = threadIdx.x;
  int g = blockIdx.x * 1024 + t;
  unsigned v = (g < n) ? in[g] : 0u;
  tmp[t] = v;
  __syncthreads();
  for (int off = 1; off < 1024; off <<= 1) {
    unsigned add = (t >= off) ? tmp[t - off] : 0u;
    __syncthreads();
    tmp[t] += add;
    __syncthreads();
  }
  if (g < n) excl[g] = tmp[t] - v;
  if (t == 1023) partials[blockIdx.x] = tmp[t];
}

__global__ void scan_partials(unsigned* __restrict__ partials, int nb) {
  __shared__ unsigned tmp[1024];
  int t = threadIdx.x;
  unsigned v = (t < nb) ? partials[t] : 0u;
  tmp[t] = v;
  __syncthreads();
  for (int off = 1; off < 1024; off <<= 1) {
    unsigned add = (t >= off) ? tmp[t - off] : 0u;
    __syncthreads();
    tmp[t] += add;
    __syncthreads();
  }
  if (t < nb) partials[t] = tmp[t] - v;   // exclusive
}

__global__ void finalize_rowptr(const unsigned* __restrict__ excl, const unsigned* __restrict__ partials,
                                unsigned* __restrict__ row_ptr, unsigned* __restrict__ cursor,
                                int n, int nE) {
  int g = blockIdx.x * blockDim.x + threadIdx.x;
  if (g < n) {
    unsigned v = excl[g] + partials[g >> 10];
    row_ptr[g] = v;
    cursor[g]  = v;
  }
  if (g == 0) row_ptr[n] = (unsigned)nE;
}

__global__ void scatter_kernel(const int* __restrict__ src, const int* __restrict__ dst,
                               unsigned* __restrict__ cursor, unsigned* __restrict__ edge_src, int nE) {
  int i = blockIdx.x * blockDim.x + threadIdx.x;
  if (i < nE) {
    unsigned pos = atomicAdd(&cursor[dst[i]], 1u);
    edge_src[pos] = (unsigned)src[i];
  }
}

// ---------------- SpMM variants ----------------

// CSR wave-per-node gather: G[d][c] = dnorm[d] * sum_{e: dst=d} X[src_e][c]
__global__ void spmm_f32row(const float* __restrict__ X, const unsigned* __restrict__ row_ptr,
                            const unsigned* __restrict__ edge_src, const float* __restrict__ dnorm,
                            float* __restrict__ G, int nN) {
  int wid  = (blockIdx.x * blockDim.x + threadIdx.x) >> 6;
  int lane = threadIdx.x & 63;
  if (wid >= nN) return;
  unsigned start = row_ptr[wid];
  int cnt = (int)(row_ptr[wid + 1] - start);
  float a0 = 0.f, a1 = 0.f, a2 = 0.f, a3 = 0.f;
  int colbase = lane * 4;
  for (int base = 0; base < cnt; base += 64) {
    int m = cnt - base; if (m > 64) m = 64;
    unsigned myidx = (lane < m) ? edge_src[start + base + lane] : 0u;
    int e = 0;
    for (; e + 1 < m; e += 2) {
      unsigned s0 = __shfl(myidx, e);
      unsigned s1 = __shfl(myidx, e + 1);
      float4 v0 = *(const float4*)(X + (size_t)s0 * FEATS + colbase);
      float4 v1 = *(const float4*)(X + (size_t)s1 * FEATS + colbase);
      a0 += v0.x; a1 += v0.y; a2 += v0.z; a3 += v0.w;
      a0 += v1.x; a1 += v1.y; a2 += v1.z; a3 += v1.w;
    }
    if (e < m) {
      unsigned s0 = __shfl(myidx, e);
      float4 v0 = *(const float4*)(X + (size_t)s0 * FEATS + colbase);
      a0 += v0.x; a1 += v0.y; a2 += v0.z; a3 += v0.w;
    }
  }
  float sc = dnorm[wid];
  *(float4*)(G + (size_t)wid * FEATS + colbase) =
      make_float4(a0 * sc, a1 * sc, a2 * sc, a3 * sc);
}

// fallback: edge-parallel atomic scatter (known good, slow)
__global__ void spmm_atomic256(const float* __restrict__ X, const int* __restrict__ src,
                               const int* __restrict__ dst, float* __restrict__ G, int nE) {
  int t = blockIdx.x * blockDim.x + threadIdx.x;
  if (t >= nE * 64) return;
  int e  = t >> 6;
  int cg = (t & 63) * 4;
  int s = src[e], d = dst[e];
  float4 v = *(const float4*)(X + (size_t)s * FEATS + cg);
  float* g = G + (size_t)d * FEATS + cg;
  atomicAdd(g + 0, v.x);
  atomicAdd(g + 1, v.y);
  atomicAdd(g + 2, v.z);
  atomicAdd(g + 3, v.w);
}

// G[i] *= dnorm[i >> 8]   (dst-norm scaling for the atomic path, 256-dim)
__global__ void scale_g256(float* __restrict__ G, const float* __restrict__ dnorm, int total) {
  int i = blockIdx.x * blockDim.x + threadIdx.x;
  if (i < total) G[i] *= dnorm[i >> 8];
}

// final layer aggregate (64-dim) via atomics — known good
__global__ void spmm_atomic64(const float* __restrict__ X, const int* __restrict__ src,
                              const int* __restrict__ dst, float* __restrict__ out, int nE) {
  int t = blockIdx.x * blockDim.x + threadIdx.x;
  if (t >= nE * 16) return;
  int e  = t >> 4;
  int cg = (t & 15) * 4;
  int s = src[e], d = dst[e];
  float4 v = *(const float4*)(X + (size_t)s * 64 + cg);
  float* g = out + (size_t)d * 64 + cg;
  atomicAdd(g + 0, v.x);
  atomicAdd(g + 1, v.y);
  atomicAdd(g + 2, v.z);
  atomicAdd(g + 3, v.w);
}

__global__ void scale_out64(float* __restrict__ out, const float* __restrict__ dnorm, int total) {
  int i = blockIdx.x * blockDim.x + threadIdx.x;
  if (i < total) out[i] *= dnorm[i >> 6];
}

// ---------------- GEMM: wave-per-row VALU fp32 (known good) ----------------
// out[r][c] = f( dn[r] * dot(A[r][:], W[:][c]) ); W is [256][N] row-major (original layout)

template<int NJ, bool RELU, bool SCDN, bool SCSN>
__global__ __launch_bounds__(256)
void gemm_row(const float* __restrict__ A, const float* __restrict__ W,
              const float* __restrict__ dnorm, const float* __restrict__ snorm,
              float* __restrict__ out, int nN) {
  const int N = NJ * 64;
  int wid  = (blockIdx.x * blockDim.x + threadIdx.x) >> 6;
  int lane = threadIdx.x & 63;
  if (wid >= nN) return;
  const float* Arow = A + (size_t)wid * 256;
  float acc[NJ];
#pragma unroll
  for (int j = 0; j < NJ; ++j) acc[j] = 0.f;

#pragma unroll 4
  for (int k = 0; k < 256; ++k) {
    float a = Arow[k];
    const float* wr = W + (size_t)k * N + lane;
#pragma unroll
    for (int j = 0; j < NJ; ++j) acc[j] = fmaf(a, wr[j * 64], acc[j]);
  }

  float dn = SCDN ? dnorm[wid] : 1.f;
  float sn = SCSN ? snorm[wid] : 1.f;
  float* orow = out + (size_t)wid * N + lane;
#pragma unroll
  for (int j = 0; j < NJ; ++j) {
    float v = acc[j];
    if (SCDN) v *= dn;
    if (RELU) v = fmaxf(v, 0.f);
    if (SCSN) v *= sn;
    orow[j * 64] = v;
  }
}

// ---------------- launch ----------------

extern "C" void kernel_launch(void* const* d_in, const int* in_sizes, int n_in,
                              void* d_out, int out_size, void* d_ws, size_t ws_size,
                              hipStream_t stream) {
  const float* feat = (const float*)d_in[0];
  const int*   src  = (const int*)d_in[1];
  const int*   dst  = (const int*)d_in[2];
  const float* W0   = (const float*)d_in[3];
  const float* W1   = (const float*)d_in[4];
  const float* W2   = (const float*)d_in[5];
  const int nE = in_sizes[1];
  const int nN = in_sizes[0] / FEATS;

  char* p = (char*)d_ws;
  auto alloc = [&](size_t bytes) -> void* {
    void* r = (void*)p;
    p += (bytes + 255) & ~(size_t)255;
    return r;
  };
  // base buffers (fallback path needs only these)
  unsigned* outdeg = (unsigned*)alloc((size_t)nN * 4);
  unsigned* indeg  = (unsigned*)alloc((size_t)nN * 4);
  float*    snorm  = (float*)   alloc((size_t)nN * 4);
  float*    dnorm  = (float*)   alloc((size_t)nN * 4);
  float*    X      = (float*)   alloc((size_t)nN * 256 * 4);  // X1 / F1 / F2
  float*    G      = (float*)   alloc((size_t)nN * 256 * 4);  // agg buffer; layer-3 H3 reuses
  // CSR buffers (allocated last; used only if they fit)
  unsigned* excl     = (unsigned*)alloc((size_t)nN * 4);
  unsigned* partials = (unsigned*)alloc(1024 * 4);
  unsigned* row_ptr  = (unsigned*)alloc(((size_t)nN + 1) * 4);
  unsigned* cursor   = (unsigned*)alloc((size_t)nN * 4);
  unsigned* edge_src = (unsigned*)alloc((size_t)nE * 4);
  const bool use_csr = ((size_t)(p - (char*)d_ws) <= ws_size);

  hipMemsetAsync(outdeg, 0, (size_t)nN * 4, stream);
  hipMemsetAsync(indeg,  0, (size_t)nN * 4, stream);

  const int TB = 256;
  int gE  = (nE + TB - 1) / TB;
  int gN  = (nN + TB - 1) / TB;
  int nb  = (nN + 1023) / 1024;
  int gRow   = (nN * 64 + TB - 1) / TB;   // wave per row/node
  int gAg256 = (nE * 64 + TB - 1) / TB;
  int gAg64  = (nE * 16 + TB - 1) / TB;

  deg_kernel<<<gE, TB, 0, stream>>>(src, dst, outdeg, indeg, nE);
  norm_kernel<<<gN, TB, 0, stream>>>(outdeg, indeg, snorm, dnorm, nN);

  int total4 = nN * (FEATS / 4);
  prescale<<<(total4 + TB - 1) / TB, TB, 0, stream>>>(feat, snorm, X, total4);

  if (use_csr) {
    scan_blocks<<<nb, 1024, 0, stream>>>(indeg, excl, partials, nN);
    scan_partials<<<1, 1024, 0, stream>>>(partials, nb);
    finalize_rowptr<<<gN, TB, 0, stream>>>(excl, partials, row_ptr, cursor, nN, nE);
    scatter_kernel<<<gE, TB, 0, stream>>>(src, dst, cursor, edge_src, nE);

    // layer 1: G = dn * seg_sum(X[src]); F1 = relu(G @ W0)*sn -> X
    spmm_f32row<<<gRow, TB, 0, stream>>>(X, row_ptr, edge_src, dnorm, G, nN);
    gemm_row<4, true, false, true><<<gRow, TB, 0, stream>>>(G, W0, nullptr, snorm, X, nN);
    // layer 2
    spmm_f32row<<<gRow, TB, 0, stream>>>(X, row_ptr, edge_src, dnorm, G, nN);
    gemm_row<4, true, false, true><<<gRow, TB, 0, stream>>>(G, W1, nullptr, snorm, X, nN);
  } else {
    // layer 1 (atomic fallback): dn applied inside gemm_row (SCDN)
    hipMemsetAsync(G, 0, (size_t)nN * 256 * 4, stream);
    spmm_atomic256<<<gAg256, TB, 0, stream>>>(X, src, dst, G, nE);
    gemm_row<4, true, true, true><<<gRow, TB, 0, stream>>>(G, W0, dnorm, snorm, X, nN);
    // layer 2
    hipMemsetAsync(G, 0, (size_t)nN * 256 * 4, stream);
    spmm_atomic256<<<gAg256, TB, 0, stream>>>(X, src, dst, G, nE);
    gemm_row<4, true, true, true><<<gRow, TB, 0, stream>>>(G, W1, dnorm, snorm, X, nN);
  }

  // layer 3: H3 = X @ W2 (no relu/scale) -> G; out = dn * seg_sum(H3[src])  (atomic, known good)
  gemm_row<1, false, false, false><<<gRow, TB, 0, stream>>>(X, W2, nullptr, nullptr, G, nN);
  hipMemsetAsync(d_out, 0, (size_t)nN * 64 * 4, stream);
  spmm_atomic64<<<gAg64, TB, 0, stream>>>(G, src, dst, (float*)d_out, nE);
  scale_out64<<<(nN * 64 + TB - 1) / TB, TB, 0, stream>>>((float*)d_out, dnorm, nN * 64);
}

// Round 8
// 3895.718 us; speedup vs baseline: 6.8449x; 1.7049x over previous
//
#include <hip/hip_runtime.h>

// GCN: 3-layer graph conv, N=100000 nodes, E=3.2M edges, feats 256->256->256->64.
// R8 = R6 + final-layer aggregation via CSR gather using the PROVEN loop structure
// (all 64 lanes iterate all edges, uniform shfl broadcast, lane=column, unconditional
// store) — replacing the buggy half-split spmm64 that caused R1-R4/R7 failures.

#define FEATS 256

// ---------------- graph prep ----------------

__global__ void deg_kernel(const int* __restrict__ src, const int* __restrict__ dst,
                           unsigned* __restrict__ outd, unsigned* __restrict__ ind, int nE) {
  int i = blockIdx.x * blockDim.x + threadIdx.x;
  if (i < nE) {
    atomicAdd(&outd[src[i]], 1u);
    atomicAdd(&ind[dst[i]], 1u);
  }
}

__global__ void norm_kernel(const unsigned* __restrict__ outd, const unsigned* __restrict__ ind,
                            float* __restrict__ snorm, float* __restrict__ dnorm, int nN) {
  int i = blockIdx.x * blockDim.x + threadIdx.x;
  if (i < nN) {
    unsigned od = outd[i]; if (od < 1u) od = 1u;
    unsigned id = ind[i];  if (id < 1u) id = 1u;
    snorm[i] = 1.0f / sqrtf((float)od);
    dnorm[i] = 1.0f / sqrtf((float)id);
  }
}

// X1[n][c] = feat[n][c] * snorm[n]   (fp32)
__global__ void prescale(const float* __restrict__ feat, const float* __restrict__ snorm,
                         float* __restrict__ X1, int total4 /* nN*64 */) {
  int i4 = blockIdx.x * blockDim.x + threadIdx.x;
  if (i4 >= total4) return;
  float4 v = ((const float4*)feat)[i4];
  float s = snorm[i4 >> 6];
  v.x *= s; v.y *= s; v.z *= s; v.w *= s;
  ((float4*)X1)[i4] = v;
}

// ---------------- CSR build ----------------

__global__ void scan_blocks(const unsigned* __restrict__ in, unsigned* __restrict__ excl,
                            unsigned* __restrict__ partials, int n) {
  __shared__ unsigned tmp[1024];
  int t = threadIdx.x;
  int g = blockIdx.x * 1024 + t;
  unsigned v = (g < n) ? in[g] : 0u;
  tmp[t] = v;
  __syncthreads();
  for (int off = 1; off < 1024; off <<= 1) {
    unsigned add = (t >= off) ? tmp[t - off] : 0u;
    __syncthreads();
    tmp[t] += add;
    __syncthreads();
  }
  if (g < n) excl[g] = tmp[t] - v;
  if (t == 1023) partials[blockIdx.x] = tmp[t];
}

__global__ void scan_partials(unsigned* __restrict__ partials, int nb) {
  __shared__ unsigned tmp[1024];
  int t = threadIdx.x;
  unsigned v = (t < nb) ? partials[t] : 0u;
  tmp[t] = v;
  __syncthreads();
  for (int off = 1; off < 1024; off <<= 1) {
    unsigned add = (t >= off) ? tmp[t - off] : 0u;
    __syncthreads();
    tmp[t] += add;
    __syncthreads();
  }
  if (t < nb) partials[t] = tmp[t] - v;   // exclusive
}

__global__ void finalize_rowptr(const unsigned* __restrict__ excl, const unsigned* __restrict__ partials,
                                unsigned* __restrict__ row_ptr, unsigned* __restrict__ cursor,
                                int n, int nE) {
  int g = blockIdx.x * blockDim.x + threadIdx.x;
  if (g < n) {
    unsigned v = excl[g] + partials[g >> 10];
    row_ptr[g] = v;
    cursor[g]  = v;
  }
  if (g == 0) row_ptr[n] = (unsigned)nE;
}

__global__ void scatter_kernel(const int* __restrict__ src, const int* __restrict__ dst,
                               unsigned* __restrict__ cursor, unsigned* __restrict__ edge_src, int nE) {
  int i = blockIdx.x * blockDim.x + threadIdx.x;
  if (i < nE) {
    unsigned pos = atomicAdd(&cursor[dst[i]], 1u);
    edge_src[pos] = (unsigned)src[i];
  }
}

// ---------------- SpMM (CSR gather) ----------------

// G[d][c] = dnorm[d] * sum_{e: dst=d} X[src_e][c], 256 cols, one wave per node  [PROVEN]
__global__ void spmm_f32row(const float* __restrict__ X, const unsigned* __restrict__ row_ptr,
                            const unsigned* __restrict__ edge_src, const float* __restrict__ dnorm,
                            float* __restrict__ G, int nN) {
  int wid  = (blockIdx.x * blockDim.x + threadIdx.x) >> 6;
  int lane = threadIdx.x & 63;
  if (wid >= nN) return;
  unsigned start = row_ptr[wid];
  int cnt = (int)(row_ptr[wid + 1] - start);
  float a0 = 0.f, a1 = 0.f, a2 = 0.f, a3 = 0.f;
  int colbase = lane * 4;
  for (int base = 0; base < cnt; base += 64) {
    int m = cnt - base; if (m > 64) m = 64;
    unsigned myidx = (lane < m) ? edge_src[start + base + lane] : 0u;
    int e = 0;
    for (; e + 1 < m; e += 2) {
      unsigned s0 = __shfl(myidx, e);
      unsigned s1 = __shfl(myidx, e + 1);
      float4 v0 = *(const float4*)(X + (size_t)s0 * FEATS + colbase);
      float4 v1 = *(const float4*)(X + (size_t)s1 * FEATS + colbase);
      a0 += v0.x; a1 += v0.y; a2 += v0.z; a3 += v0.w;
      a0 += v1.x; a1 += v1.y; a2 += v1.z; a3 += v1.w;
    }
    if (e < m) {
      unsigned s0 = __shfl(myidx, e);
      float4 v0 = *(const float4*)(X + (size_t)s0 * FEATS + colbase);
      a0 += v0.x; a1 += v0.y; a2 += v0.z; a3 += v0.w;
    }
  }
  float sc = dnorm[wid];
  *(float4*)(G + (size_t)wid * FEATS + colbase) =
      make_float4(a0 * sc, a1 * sc, a2 * sc, a3 * sc);
}

// out[d][c] = dnorm[d] * sum_{e: dst=d} X[src_e][c], 64 cols, one wave per node.
// FIXED structure: lane = column, ALL lanes iterate ALL edges (same shape as
// spmm_f32row), unconditional store. No half-split, no shfl_down, no cond write.
__global__ void spmm64_f32(const float* __restrict__ X, const unsigned* __restrict__ row_ptr,
                           const unsigned* __restrict__ edge_src, const float* __restrict__ dnorm,
                           float* __restrict__ out, int nN) {
  int wid  = (blockIdx.x * blockDim.x + threadIdx.x) >> 6;
  int lane = threadIdx.x & 63;
  if (wid >= nN) return;
  unsigned start = row_ptr[wid];
  int cnt = (int)(row_ptr[wid + 1] - start);
  float a0 = 0.f;
  for (int base = 0; base < cnt; base += 64) {
    int m = cnt - base; if (m > 64) m = 64;
    unsigned myidx = (lane < m) ? edge_src[start + base + lane] : 0u;
    int e = 0;
    for (; e + 1 < m; e += 2) {
      unsigned s0 = __shfl(myidx, e);
      unsigned s1 = __shfl(myidx, e + 1);
      float v0 = X[(size_t)s0 * 64 + lane];
      float v1 = X[(size_t)s1 * 64 + lane];
      a0 += v0;
      a0 += v1;
    }
    if (e < m) {
      unsigned s0 = __shfl(myidx, e);
      a0 += X[(size_t)s0 * 64 + lane];
    }
  }
  out[(size_t)wid * 64 + lane] = a0 * dnorm[wid];
}

// ---------------- GEMM: wave-per-row VALU fp32 (known good) ----------------
// out[r][c] = f( dot(A[r][:], W[:][c]) ); W is [256][N] row-major (original layout)

template<int NJ, bool RELU, bool SCSN>
__global__ __launch_bounds__(256)
void gemm_row(const float* __restrict__ A, const float* __restrict__ W,
              const float* __restrict__ snorm, float* __restrict__ out, int nN) {
  const int N = NJ * 64;
  int wid  = (blockIdx.x * blockDim.x + threadIdx.x) >> 6;
  int lane = threadIdx.x & 63;
  if (wid >= nN) return;
  const float* Arow = A + (size_t)wid * 256;
  float acc[NJ];
#pragma unroll
  for (int j = 0; j < NJ; ++j) acc[j] = 0.f;

#pragma unroll 4
  for (int k = 0; k < 256; ++k) {
    float a = Arow[k];
    const float* wr = W + (size_t)k * N + lane;
#pragma unroll
    for (int j = 0; j < NJ; ++j) acc[j] = fmaf(a, wr[j * 64], acc[j]);
  }

  float sn = SCSN ? snorm[wid] : 1.f;
  float* orow = out + (size_t)wid * N + lane;
#pragma unroll
  for (int j = 0; j < NJ; ++j) {
    float v = acc[j];
    if (RELU) v = fmaxf(v, 0.f);
    if (SCSN) v *= sn;
    orow[j * 64] = v;
  }
}

// ---------------- launch ----------------

extern "C" void kernel_launch(void* const* d_in, const int* in_sizes, int n_in,
                              void* d_out, int out_size, void* d_ws, size_t ws_size,
                              hipStream_t stream) {
  const float* feat = (const float*)d_in[0];
  const int*   src  = (const int*)d_in[1];
  const int*   dst  = (const int*)d_in[2];
  const float* W0   = (const float*)d_in[3];
  const float* W1   = (const float*)d_in[4];
  const float* W2   = (const float*)d_in[5];
  const int nE = in_sizes[1];
  const int nN = in_sizes[0] / FEATS;

  char* p = (char*)d_ws;
  auto alloc = [&](size_t bytes) -> void* {
    void* r = (void*)p;
    p += (bytes + 255) & ~(size_t)255;
    return r;
  };
  unsigned* outdeg = (unsigned*)alloc((size_t)nN * 4);
  unsigned* indeg  = (unsigned*)alloc((size_t)nN * 4);
  float*    snorm  = (float*)   alloc((size_t)nN * 4);
  float*    dnorm  = (float*)   alloc((size_t)nN * 4);
  float*    X      = (float*)   alloc((size_t)nN * 256 * 4);  // X1 / F1 / F2
  float*    G      = (float*)   alloc((size_t)nN * 256 * 4);  // agg buffer; layer-3 H3 reuses
  unsigned* excl     = (unsigned*)alloc((size_t)nN * 4);
  unsigned* partials = (unsigned*)alloc(1024 * 4);
  unsigned* row_ptr  = (unsigned*)alloc(((size_t)nN + 1) * 4);
  unsigned* cursor   = (unsigned*)alloc((size_t)nN * 4);
  unsigned* edge_src = (unsigned*)alloc((size_t)nE * 4);
  // footprint == R6's proven-good 220.0 MB

  hipMemsetAsync(outdeg, 0, (size_t)nN * 4, stream);
  hipMemsetAsync(indeg,  0, (size_t)nN * 4, stream);

  const int TB = 256;
  int gE  = (nE + TB - 1) / TB;
  int gN  = (nN + TB - 1) / TB;
  int nb  = (nN + 1023) / 1024;
  int gRow = (nN * 64 + TB - 1) / TB;   // wave per row/node

  deg_kernel<<<gE, TB, 0, stream>>>(src, dst, outdeg, indeg, nE);
  norm_kernel<<<gN, TB, 0, stream>>>(outdeg, indeg, snorm, dnorm, nN);

  int total4 = nN * (FEATS / 4);
  prescale<<<(total4 + TB - 1) / TB, TB, 0, stream>>>(feat, snorm, X, total4);

  scan_blocks<<<nb, 1024, 0, stream>>>(indeg, excl, partials, nN);
  scan_partials<<<1, 1024, 0, stream>>>(partials, nb);
  finalize_rowptr<<<gN, TB, 0, stream>>>(excl, partials, row_ptr, cursor, nN, nE);
  scatter_kernel<<<gE, TB, 0, stream>>>(src, dst, cursor, edge_src, nE);

  // layer 1: G = dn * seg_sum(X[src]); F1 = relu(G @ W0)*sn -> X
  spmm_f32row<<<gRow, TB, 0, stream>>>(X, row_ptr, edge_src, dnorm, G, nN);
  gemm_row<4, true, true><<<gRow, TB, 0, stream>>>(G, W0, snorm, X, nN);
  // layer 2
  spmm_f32row<<<gRow, TB, 0, stream>>>(X, row_ptr, edge_src, dnorm, G, nN);
  gemm_row<4, true, true><<<gRow, TB, 0, stream>>>(G, W1, snorm, X, nN);
  // layer 3: H3 = X @ W2 -> G; out = dn * seg_sum(H3[src])  (fixed-structure gather)
  gemm_row<1, false, false><<<gRow, TB, 0, stream>>>(X, W2, nullptr, G, nN);
  spmm64_f32<<<gRow, TB, 0, stream>>>(G, row_ptr, edge_src, dnorm, (float*)d_out, nN);
}

// Round 9
// 2032.115 us; speedup vs baseline: 13.1222x; 1.9171x over previous
//
#include <hip/hip_runtime.h>

// GCN: 3-layer graph conv, N=100000 nodes, E=3.2M edges, feats 256->256->256->64.
// R9 = R8 + MFMA GEMM (fp32-A hi/lo split in-register, W hi/lo split, 3-term
// 16x16x32 bf16 MFMA => ~fp32 precision). Weight-split planes live in the dead
// outdeg/indeg workspace region, keeping footprint at the proven 220.0 MB.

typedef __bf16  bf16x8 __attribute__((ext_vector_type(8)));
typedef float   f32x4  __attribute__((ext_vector_type(4)));

#define FEATS 256

static __device__ __forceinline__ unsigned short f2bf(float f) {
  unsigned u = __float_as_uint(f);
  u += 0x7fffu + ((u >> 16) & 1u);          // round-to-nearest-even
  return (unsigned short)(u >> 16);
}
static __device__ __forceinline__ float bfval(unsigned short h) { return __uint_as_float((unsigned)h << 16); }

// ---------------- graph prep ----------------

__global__ void deg_kernel(const int* __restrict__ src, const int* __restrict__ dst,
                           unsigned* __restrict__ outd, unsigned* __restrict__ ind, int nE) {
  int i = blockIdx.x * blockDim.x + threadIdx.x;
  if (i < nE) {
    atomicAdd(&outd[src[i]], 1u);
    atomicAdd(&ind[dst[i]], 1u);
  }
}

__global__ void norm_kernel(const unsigned* __restrict__ outd, const unsigned* __restrict__ ind,
                            float* __restrict__ snorm, float* __restrict__ dnorm, int nN) {
  int i = blockIdx.x * blockDim.x + threadIdx.x;
  if (i < nN) {
    unsigned od = outd[i]; if (od < 1u) od = 1u;
    unsigned id = ind[i];  if (id < 1u) id = 1u;
    snorm[i] = 1.0f / sqrtf((float)od);
    dnorm[i] = 1.0f / sqrtf((float)id);
  }
}

// X1[n][c] = feat[n][c] * snorm[n]   (fp32)
__global__ void prescale(const float* __restrict__ feat, const float* __restrict__ snorm,
                         float* __restrict__ X1, int total4 /* nN*64 */) {
  int i4 = blockIdx.x * blockDim.x + threadIdx.x;
  if (i4 >= total4) return;
  float4 v = ((const float4*)feat)[i4];
  float s = snorm[i4 >> 6];
  v.x *= s; v.y *= s; v.z *= s; v.w *= s;
  ((float4*)X1)[i4] = v;
}

// ---------------- CSR build ----------------

__global__ void scan_blocks(const unsigned* __restrict__ in, unsigned* __restrict__ excl,
                            unsigned* __restrict__ partials, int n) {
  __shared__ unsigned tmp[1024];
  int t = threadIdx.x;
  int g = blockIdx.x * 1024 + t;
  unsigned v = (g < n) ? in[g] : 0u;
  tmp[t] = v;
  __syncthreads();
  for (int off = 1; off < 1024; off <<= 1) {
    unsigned add = (t >= off) ? tmp[t - off] : 0u;
    __syncthreads();
    tmp[t] += add;
    __syncthreads();
  }
  if (g < n) excl[g] = tmp[t] - v;
  if (t == 1023) partials[blockIdx.x] = tmp[t];
}

__global__ void scan_partials(unsigned* __restrict__ partials, int nb) {
  __shared__ unsigned tmp[1024];
  int t = threadIdx.x;
  unsigned v = (t < nb) ? partials[t] : 0u;
  tmp[t] = v;
  __syncthreads();
  for (int off = 1; off < 1024; off <<= 1) {
    unsigned add = (t >= off) ? tmp[t - off] : 0u;
    __syncthreads();
    tmp[t] += add;
    __syncthreads();
  }
  if (t < nb) partials[t] = tmp[t] - v;   // exclusive
}

__global__ void finalize_rowptr(const unsigned* __restrict__ excl, const unsigned* __restrict__ partials,
                                unsigned* __restrict__ row_ptr, unsigned* __restrict__ cursor,
                                int n, int nE) {
  int g = blockIdx.x * blockDim.x + threadIdx.x;
  if (g < n) {
    unsigned v = excl[g] + partials[g >> 10];
    row_ptr[g] = v;
    cursor[g]  = v;
  }
  if (g == 0) row_ptr[n] = (unsigned)nE;
}

__global__ void scatter_kernel(const int* __restrict__ src, const int* __restrict__ dst,
                               unsigned* __restrict__ cursor, unsigned* __restrict__ edge_src, int nE) {
  int i = blockIdx.x * blockDim.x + threadIdx.x;
  if (i < nE) {
    unsigned pos = atomicAdd(&cursor[dst[i]], 1u);
    edge_src[pos] = (unsigned)src[i];
  }
}

// ---------------- weight split (hi/lo, transposed) ----------------

// Wh/Wl[n][k] = split_bf16(W[k][n]);  W is K x N row-major
__global__ void cast_w_split(const float* __restrict__ W, unsigned short* __restrict__ Wh,
                             unsigned short* __restrict__ Wl, int K, int N) {
  int i = blockIdx.x * blockDim.x + threadIdx.x;
  if (i < K * N) {
    int n = i / K, k = i - n * K;
    float v = W[k * N + n];
    unsigned short h = f2bf(v);
    Wh[i] = h;
    Wl[i] = f2bf(v - bfval(h));
  }
}

// ---------------- SpMM (CSR gather) — PROVEN structure ----------------

__global__ void spmm_f32row(const float* __restrict__ X, const unsigned* __restrict__ row_ptr,
                            const unsigned* __restrict__ edge_src, const float* __restrict__ dnorm,
                            float* __restrict__ G, int nN) {
  int wid  = (blockIdx.x * blockDim.x + threadIdx.x) >> 6;
  int lane = threadIdx.x & 63;
  if (wid >= nN) return;
  unsigned start = row_ptr[wid];
  int cnt = (int)(row_ptr[wid + 1] - start);
  float a0 = 0.f, a1 = 0.f, a2 = 0.f, a3 = 0.f;
  int colbase = lane * 4;
  for (int base = 0; base < cnt; base += 64) {
    int m = cnt - base; if (m > 64) m = 64;
    unsigned myidx = (lane < m) ? edge_src[start + base + lane] : 0u;
    int e = 0;
    for (; e + 1 < m; e += 2) {
      unsigned s0 = __shfl(myidx, e);
      unsigned s1 = __shfl(myidx, e + 1);
      float4 v0 = *(const float4*)(X + (size_t)s0 * FEATS + colbase);
      float4 v1 = *(const float4*)(X + (size_t)s1 * FEATS + colbase);
      a0 += v0.x; a1 += v0.y; a2 += v0.z; a3 += v0.w;
      a0 += v1.x; a1 += v1.y; a2 += v1.z; a3 += v1.w;
    }
    if (e < m) {
      unsigned s0 = __shfl(myidx, e);
      float4 v0 = *(const float4*)(X + (size_t)s0 * FEATS + colbase);
      a0 += v0.x; a1 += v0.y; a2 += v0.z; a3 += v0.w;
    }
  }
  float sc = dnorm[wid];
  *(float4*)(G + (size_t)wid * FEATS + colbase) =
      make_float4(a0 * sc, a1 * sc, a2 * sc, a3 * sc);
}

// 64-dim: lane = column, all lanes iterate all edges (fixed structure from R8)
__global__ void spmm64_f32(const float* __restrict__ X, const unsigned* __restrict__ row_ptr,
                           const unsigned* __restrict__ edge_src, const float* __restrict__ dnorm,
                           float* __restrict__ out, int nN) {
  int wid  = (blockIdx.x * blockDim.x + threadIdx.x) >> 6;
  int lane = threadIdx.x & 63;
  if (wid >= nN) return;
  unsigned start = row_ptr[wid];
  int cnt = (int)(row_ptr[wid + 1] - start);
  float a0 = 0.f;
  for (int base = 0; base < cnt; base += 64) {
    int m = cnt - base; if (m > 64) m = 64;
    unsigned myidx = (lane < m) ? edge_src[start + base + lane] : 0u;
    int e = 0;
    for (; e + 1 < m; e += 2) {
      unsigned s0 = __shfl(myidx, e);
      unsigned s1 = __shfl(myidx, e + 1);
      a0 += X[(size_t)s0 * 64 + lane];
      a0 += X[(size_t)s1 * 64 + lane];
    }
    if (e < m) {
      unsigned s0 = __shfl(myidx, e);
      a0 += X[(size_t)s0 * 64 + lane];
    }
  }
  out[(size_t)wid * 64 + lane] = a0 * dnorm[wid];
}

// ---------------- GEMM: MFMA, fp32-A split, W hi/lo split, 3-term ----------------
// out[M x (NT*16)] = A[M x 256] @ (Wh+Wl); fused relu + per-row snorm; fp32 out.

static __device__ __forceinline__ void split8(const float* __restrict__ p, bf16x8& h, bf16x8& l) {
  float4 u = *(const float4*)p;
  float4 v = *(const float4*)(p + 4);
  float x[8] = {u.x, u.y, u.z, u.w, v.x, v.y, v.z, v.w};
#pragma unroll
  for (int j = 0; j < 8; ++j) {
    __bf16 hh = (__bf16)x[j];
    h[j] = hh;
    l[j] = (__bf16)(x[j] - (float)hh);
  }
}

template<int NT, bool RELU, bool SCALE>
__global__ __launch_bounds__(256)
void gemm_f32a(const float* __restrict__ A,
               const unsigned short* __restrict__ Wh, const unsigned short* __restrict__ Wl,
               const float* __restrict__ snorm, float* __restrict__ out, int nN) {
  __shared__ unsigned short Bh[NT * 512];   // [nt][lane][8] bf16, frag-linear
  __shared__ unsigned short Bl[NT * 512];
  const int tid  = threadIdx.x;
  const int w    = tid >> 6;
  const int lane = tid & 63;
  const int quad = lane >> 4;
  const int l16  = lane & 15;
  const int m0   = blockIdx.x * 128 + w * 32;

  f32x4 acc0[NT], acc1[NT];
#pragma unroll
  for (int i = 0; i < NT; ++i) { acc0[i] = (f32x4){0.f,0.f,0.f,0.f}; acc1[i] = (f32x4){0.f,0.f,0.f,0.f}; }

  int r0 = m0 + l16;  int rc0 = (r0 < nN) ? r0 : (nN - 1);
  int r1 = r0 + 16;   int rc1 = (r1 < nN) ? r1 : (nN - 1);
  const size_t abase0 = (size_t)rc0 * 256 + quad * 8;
  const size_t abase1 = (size_t)rc1 * 256 + quad * 8;

  constexpr int CH = (NT * 64) / 256;   // LDS chunks per thread per plane

  for (int kk = 0; kk < 8; ++kk) {
    __syncthreads();
#pragma unroll
    for (int j = 0; j < CH; ++j) {
      int ch = tid + j * 256;
      int nt = ch >> 6; int L = ch & 63;
      int n  = nt * 16 + (L & 15);
      int kb = (L >> 4) * 8;
      *(int4*)(Bh + ch * 8) = *(const int4*)(Wh + n * 256 + kk * 32 + kb);
      *(int4*)(Bl + ch * 8) = *(const int4*)(Wl + n * 256 + kk * 32 + kb);
    }
    __syncthreads();
    bf16x8 ah0, al0, ah1, al1;
    split8(A + abase0 + kk * 32, ah0, al0);
    split8(A + abase1 + kk * 32, ah1, al1);
#pragma unroll
    for (int nt = 0; nt < NT; ++nt) {
      bf16x8 bh = *(const bf16x8*)(Bh + nt * 512 + lane * 8);
      bf16x8 bl = *(const bf16x8*)(Bl + nt * 512 + lane * 8);
      acc0[nt] = __builtin_amdgcn_mfma_f32_16x16x32_bf16(ah0, bh, acc0[nt], 0, 0, 0);
      acc1[nt] = __builtin_amdgcn_mfma_f32_16x16x32_bf16(ah1, bh, acc1[nt], 0, 0, 0);
      acc0[nt] = __builtin_amdgcn_mfma_f32_16x16x32_bf16(al0, bh, acc0[nt], 0, 0, 0);
      acc1[nt] = __builtin_amdgcn_mfma_f32_16x16x32_bf16(al1, bh, acc1[nt], 0, 0, 0);
      acc0[nt] = __builtin_amdgcn_mfma_f32_16x16x32_bf16(ah0, bl, acc0[nt], 0, 0, 0);
      acc1[nt] = __builtin_amdgcn_mfma_f32_16x16x32_bf16(ah1, bl, acc1[nt], 0, 0, 0);
    }
  }

  // epilogue: C/D layout col=lane&15, row=quad*4+reg
  const int N = NT * 16;
#pragma unroll
  for (int reg = 0; reg < 4; ++reg) {
    int rr0 = m0 + quad * 4 + reg;
    int rr1 = rr0 + 16;
    float s0 = 1.f, s1 = 1.f;
    if (SCALE) {
      s0 = snorm[(rr0 < nN) ? rr0 : 0];
      s1 = snorm[(rr1 < nN) ? rr1 : 0];
    }
#pragma unroll
    for (int nt = 0; nt < NT; ++nt) {
      if (rr0 < nN) {
        float v = acc0[nt][reg];
        if (RELU) v = fmaxf(v, 0.f);
        if (SCALE) v *= s0;
        out[(size_t)rr0 * N + nt * 16 + l16] = v;
      }
      if (rr1 < nN) {
        float v = acc1[nt][reg];
        if (RELU) v = fmaxf(v, 0.f);
        if (SCALE) v *= s1;
        out[(size_t)rr1 * N + nt * 16 + l16] = v;
      }
    }
  }
}

// ---------------- launch ----------------

extern "C" void kernel_launch(void* const* d_in, const int* in_sizes, int n_in,
                              void* d_out, int out_size, void* d_ws, size_t ws_size,
                              hipStream_t stream) {
  const float* feat = (const float*)d_in[0];
  const int*   src  = (const int*)d_in[1];
  const int*   dst  = (const int*)d_in[2];
  const float* W0   = (const float*)d_in[3];
  const float* W1   = (const float*)d_in[4];
  const float* W2   = (const float*)d_in[5];
  const int nE = in_sizes[1];
  const int nN = in_sizes[0] / FEATS;

  char* p = (char*)d_ws;
  auto alloc = [&](size_t bytes) -> void* {
    void* r = (void*)p;
    p += (bytes + 255) & ~(size_t)255;
    return r;
  };
  unsigned* outdeg = (unsigned*)alloc((size_t)nN * 4);
  unsigned* indeg  = (unsigned*)alloc((size_t)nN * 4);
  float*    snorm  = (float*)   alloc((size_t)nN * 4);
  float*    dnorm  = (float*)   alloc((size_t)nN * 4);
  float*    X      = (float*)   alloc((size_t)nN * 256 * 4);  // X1 / F1 / F2
  float*    G      = (float*)   alloc((size_t)nN * 256 * 4);  // agg buffer; layer-3 H3 reuses
  unsigned* excl     = (unsigned*)alloc((size_t)nN * 4);
  unsigned* partials = (unsigned*)alloc(1024 * 4);
  unsigned* row_ptr  = (unsigned*)alloc(((size_t)nN + 1) * 4);
  unsigned* cursor   = (unsigned*)alloc((size_t)nN * 4);
  unsigned* edge_src = (unsigned*)alloc((size_t)nE * 4);
  // footprint == R6/R8's proven-good 220.0 MB

  // Weight hi/lo planes (576 KB) alias the outdeg/indeg region (800 KB contig),
  // which is dead after norm_kernel/scan_blocks. Cast AFTER scatter for safety.
  unsigned short* W0h = (unsigned short*)outdeg;
  unsigned short* W0l = W0h + 256 * 256;
  unsigned short* W1h = W0l + 256 * 256;
  unsigned short* W1l = W1h + 256 * 256;
  unsigned short* W2h = W1l + 256 * 256;
  unsigned short* W2l = W2h + 64 * 256;   // ends at 589824 B < 800256 B region

  hipMemsetAsync(outdeg, 0, (size_t)nN * 4, stream);
  hipMemsetAsync(indeg,  0, (size_t)nN * 4, stream);

  const int TB = 256;
  int gE  = (nE + TB - 1) / TB;
  int gN  = (nN + TB - 1) / TB;
  int nb  = (nN + 1023) / 1024;
  int gRow = (nN * 64 + TB - 1) / TB;   // wave per row/node
  int gGm  = (nN + 127) / 128;          // MFMA gemm: 128 rows/block

  deg_kernel<<<gE, TB, 0, stream>>>(src, dst, outdeg, indeg, nE);
  norm_kernel<<<gN, TB, 0, stream>>>(outdeg, indeg, snorm, dnorm, nN);

  int total4 = nN * (FEATS / 4);
  prescale<<<(total4 + TB - 1) / TB, TB, 0, stream>>>(feat, snorm, X, total4);

  scan_blocks<<<nb, 1024, 0, stream>>>(indeg, excl, partials, nN);
  scan_partials<<<1, 1024, 0, stream>>>(partials, nb);
  finalize_rowptr<<<gN, TB, 0, stream>>>(excl, partials, row_ptr, cursor, nN, nE);
  scatter_kernel<<<gE, TB, 0, stream>>>(src, dst, cursor, edge_src, nE);

  // weight splits into the dead outdeg/indeg region (all uses of outdeg/indeg done)
  cast_w_split<<<(256 * 256 + TB - 1) / TB, TB, 0, stream>>>(W0, W0h, W0l, 256, 256);
  cast_w_split<<<(256 * 256 + TB - 1) / TB, TB, 0, stream>>>(W1, W1h, W1l, 256, 256);
  cast_w_split<<<(256 * 64  + TB - 1) / TB, TB, 0, stream>>>(W2, W2h, W2l, 256, 64);

  // layer 1: G = dn * seg_sum(X[src]); F1 = relu(G @ W0)*sn -> X
  spmm_f32row<<<gRow, TB, 0, stream>>>(X, row_ptr, edge_src, dnorm, G, nN);
  gemm_f32a<16, true, true><<<gGm, TB, 0, stream>>>(G, W0h, W0l, snorm, X, nN);
  // layer 2
  spmm_f32row<<<gRow, TB, 0, stream>>>(X, row_ptr, edge_src, dnorm, G, nN);
  gemm_f32a<16, true, true><<<gGm, TB, 0, stream>>>(G, W1h, W1l, snorm, X, nN);
  // layer 3: H3 = X @ W2 -> G; out = dn * seg_sum(H3[src])
  gemm_f32a<4, false, false><<<gGm, TB, 0, stream>>>(X, W2h, W2l, nullptr, G, nN);
  spmm64_f32<<<gRow, TB, 0, stream>>>(G, row_ptr, edge_src, dnorm, (float*)d_out, nN);
}

// Round 10
// 1550.032 us; speedup vs baseline: 17.2034x; 1.3110x over previous
//
#include <hip/hip_runtime.h>

// GCN: 3-layer graph conv, N=100000 nodes, E=3.2M edges, feats 256->256->256->64.
// R10 = R9 + bf16 gather inputs for the two 256-dim aggregations:
//   X1 (feat*snorm) and F1 (layer-1 activations) stored as bf16 -> gather reads halve.
//   SpMM accumulates fp32, writes G fp32; MFMA GEMM (3-term split) unchanged.
//   Layer 3 stays fully fp32. Footprint unchanged (bf16 lives inside the X region).

typedef __bf16  bf16x8 __attribute__((ext_vector_type(8)));
typedef float   f32x4  __attribute__((ext_vector_type(4)));

#define FEATS 256

static __device__ __forceinline__ unsigned short f2bf(float f) {
  unsigned u = __float_as_uint(f);
  u += 0x7fffu + ((u >> 16) & 1u);          // round-to-nearest-even
  return (unsigned short)(u >> 16);
}
static __device__ __forceinline__ float bfval(unsigned short h) { return __uint_as_float((unsigned)h << 16); }
static __device__ __forceinline__ float bflo(unsigned u) { return __uint_as_float(u << 16); }
static __device__ __forceinline__ float bfhi(unsigned u) { return __uint_as_float(u & 0xffff0000u); }

// ---------------- graph prep ----------------

__global__ void deg_kernel(const int* __restrict__ src, const int* __restrict__ dst,
                           unsigned* __restrict__ outd, unsigned* __restrict__ ind, int nE) {
  int i = blockIdx.x * blockDim.x + threadIdx.x;
  if (i < nE) {
    atomicAdd(&outd[src[i]], 1u);
    atomicAdd(&ind[dst[i]], 1u);
  }
}

__global__ void norm_kernel(const unsigned* __restrict__ outd, const unsigned* __restrict__ ind,
                            float* __restrict__ snorm, float* __restrict__ dnorm, int nN) {
  int i = blockIdx.x * blockDim.x + threadIdx.x;
  if (i < nN) {
    unsigned od = outd[i]; if (od < 1u) od = 1u;
    unsigned id = ind[i];  if (id < 1u) id = 1u;
    snorm[i] = 1.0f / sqrtf((float)od);
    dnorm[i] = 1.0f / sqrtf((float)id);
  }
}

// Xb[n][c] = bf16(feat[n][c] * snorm[n]); thread handles 8 elems
__global__ void prescale_bf16(const float* __restrict__ feat, const float* __restrict__ snorm,
                              unsigned short* __restrict__ Xb, int total8 /* nN*32 */) {
  int i8 = blockIdx.x * blockDim.x + threadIdx.x;
  if (i8 >= total8) return;
  float4 u = ((const float4*)feat)[i8 * 2];
  float4 v = ((const float4*)feat)[i8 * 2 + 1];
  float s = snorm[i8 >> 5];
  uint2 a, b;
  a.x = (unsigned)f2bf(u.x * s) | ((unsigned)f2bf(u.y * s) << 16);
  a.y = (unsigned)f2bf(u.z * s) | ((unsigned)f2bf(u.w * s) << 16);
  b.x = (unsigned)f2bf(v.x * s) | ((unsigned)f2bf(v.y * s) << 16);
  b.y = (unsigned)f2bf(v.z * s) | ((unsigned)f2bf(v.w * s) << 16);
  *(uint4*)(Xb + (size_t)i8 * 8) = make_uint4(a.x, a.y, b.x, b.y);
}

// ---------------- CSR build ----------------

__global__ void scan_blocks(const unsigned* __restrict__ in, unsigned* __restrict__ excl,
                            unsigned* __restrict__ partials, int n) {
  __shared__ unsigned tmp[1024];
  int t = threadIdx.x;
  int g = blockIdx.x * 1024 + t;
  unsigned v = (g < n) ? in[g] : 0u;
  tmp[t] = v;
  __syncthreads();
  for (int off = 1; off < 1024; off <<= 1) {
    unsigned add = (t >= off) ? tmp[t - off] : 0u;
    __syncthreads();
    tmp[t] += add;
    __syncthreads();
  }
  if (g < n) excl[g] = tmp[t] - v;
  if (t == 1023) partials[blockIdx.x] = tmp[t];
}

__global__ void scan_partials(unsigned* __restrict__ partials, int nb) {
  __shared__ unsigned tmp[1024];
  int t = threadIdx.x;
  unsigned v = (t < nb) ? partials[t] : 0u;
  tmp[t] = v;
  __syncthreads();
  for (int off = 1; off < 1024; off <<= 1) {
    unsigned add = (t >= off) ? tmp[t - off] : 0u;
    __syncthreads();
    tmp[t] += add;
    __syncthreads();
  }
  if (t < nb) partials[t] = tmp[t] - v;   // exclusive
}

__global__ void finalize_rowptr(const unsigned* __restrict__ excl, const unsigned* __restrict__ partials,
                                unsigned* __restrict__ row_ptr, unsigned* __restrict__ cursor,
                                int n, int nE) {
  int g = blockIdx.x * blockDim.x + threadIdx.x;
  if (g < n) {
    unsigned v = excl[g] + partials[g >> 10];
    row_ptr[g] = v;
    cursor[g]  = v;
  }
  if (g == 0) row_ptr[n] = (unsigned)nE;
}

__global__ void scatter_kernel(const int* __restrict__ src, const int* __restrict__ dst,
                               unsigned* __restrict__ cursor, unsigned* __restrict__ edge_src, int nE) {
  int i = blockIdx.x * blockDim.x + threadIdx.x;
  if (i < nE) {
    unsigned pos = atomicAdd(&cursor[dst[i]], 1u);
    edge_src[pos] = (unsigned)src[i];
  }
}

// ---------------- weight split (hi/lo, transposed) ----------------

__global__ void cast_w_split(const float* __restrict__ W, unsigned short* __restrict__ Wh,
                             unsigned short* __restrict__ Wl, int K, int N) {
  int i = blockIdx.x * blockDim.x + threadIdx.x;
  if (i < K * N) {
    int n = i / K, k = i - n * K;
    float v = W[k * N + n];
    unsigned short h = f2bf(v);
    Wh[i] = h;
    Wl[i] = f2bf(v - bfval(h));
  }
}

// ---------------- SpMM (CSR gather) — PROVEN loop structure ----------------

// bf16 input: G[d][c] = dnorm[d] * sum_{e: dst=d} Xb[src_e][c]; fp32 accum/out
__global__ void spmm_bf16row(const unsigned short* __restrict__ Xb, const unsigned* __restrict__ row_ptr,
                             const unsigned* __restrict__ edge_src, const float* __restrict__ dnorm,
                             float* __restrict__ G, int nN) {
  int wid  = (blockIdx.x * blockDim.x + threadIdx.x) >> 6;
  int lane = threadIdx.x & 63;
  if (wid >= nN) return;
  unsigned start = row_ptr[wid];
  int cnt = (int)(row_ptr[wid + 1] - start);
  float a0 = 0.f, a1 = 0.f, a2 = 0.f, a3 = 0.f;
  int colbase = lane * 4;
  for (int base = 0; base < cnt; base += 64) {
    int m = cnt - base; if (m > 64) m = 64;
    unsigned myidx = (lane < m) ? edge_src[start + base + lane] : 0u;
    int e = 0;
    for (; e + 1 < m; e += 2) {
      unsigned s0 = __shfl(myidx, e);
      unsigned s1 = __shfl(myidx, e + 1);
      uint2 d0 = *(const uint2*)(Xb + (size_t)s0 * FEATS + colbase);
      uint2 d1 = *(const uint2*)(Xb + (size_t)s1 * FEATS + colbase);
      a0 += bflo(d0.x); a1 += bfhi(d0.x); a2 += bflo(d0.y); a3 += bfhi(d0.y);
      a0 += bflo(d1.x); a1 += bfhi(d1.x); a2 += bflo(d1.y); a3 += bfhi(d1.y);
    }
    if (e < m) {
      unsigned s0 = __shfl(myidx, e);
      uint2 d0 = *(const uint2*)(Xb + (size_t)s0 * FEATS + colbase);
      a0 += bflo(d0.x); a1 += bfhi(d0.x); a2 += bflo(d0.y); a3 += bfhi(d0.y);
    }
  }
  float sc = dnorm[wid];
  *(float4*)(G + (size_t)wid * FEATS + colbase) =
      make_float4(a0 * sc, a1 * sc, a2 * sc, a3 * sc);
}

// 64-dim fp32: lane = column, all lanes iterate all edges (proven R8 kernel, untouched)
__global__ void spmm64_f32(const float* __restrict__ X, const unsigned* __restrict__ row_ptr,
                           const unsigned* __restrict__ edge_src, const float* __restrict__ dnorm,
                           float* __restrict__ out, int nN) {
  int wid  = (blockIdx.x * blockDim.x + threadIdx.x) >> 6;
  int lane = threadIdx.x & 63;
  if (wid >= nN) return;
  unsigned start = row_ptr[wid];
  int cnt = (int)(row_ptr[wid + 1] - start);
  float a0 = 0.f;
  for (int base = 0; base < cnt; base += 64) {
    int m = cnt - base; if (m > 64) m = 64;
    unsigned myidx = (lane < m) ? edge_src[start + base + lane] : 0u;
    int e = 0;
    for (; e + 1 < m; e += 2) {
      unsigned s0 = __shfl(myidx, e);
      unsigned s1 = __shfl(myidx, e + 1);
      a0 += X[(size_t)s0 * 64 + lane];
      a0 += X[(size_t)s1 * 64 + lane];
    }
    if (e < m) {
      unsigned s0 = __shfl(myidx, e);
      a0 += X[(size_t)s0 * 64 + lane];
    }
  }
  out[(size_t)wid * 64 + lane] = a0 * dnorm[wid];
}

// ---------------- GEMM: MFMA, fp32-A split, W hi/lo split, 3-term ----------------

static __device__ __forceinline__ void split8(const float* __restrict__ p, bf16x8& h, bf16x8& l) {
  float4 u = *(const float4*)p;
  float4 v = *(const float4*)(p + 4);
  float x[8] = {u.x, u.y, u.z, u.w, v.x, v.y, v.z, v.w};
#pragma unroll
  for (int j = 0; j < 8; ++j) {
    __bf16 hh = (__bf16)x[j];
    h[j] = hh;
    l[j] = (__bf16)(x[j] - (float)hh);
  }
}

static __device__ __forceinline__ void storev(unsigned short* p, float v) { *p = f2bf(v); }
static __device__ __forceinline__ void storev(float* p, float v) { *p = v; }

template<int NT, bool RELU, bool SCALE, typename OutT>
__global__ __launch_bounds__(256)
void gemm_f32a(const float* __restrict__ A,
               const unsigned short* __restrict__ Wh, const unsigned short* __restrict__ Wl,
               const float* __restrict__ snorm, OutT* __restrict__ out, int nN) {
  __shared__ unsigned short Bh[NT * 512];   // [nt][lane][8] bf16, frag-linear
  __shared__ unsigned short Bl[NT * 512];
  const int tid  = threadIdx.x;
  const int w    = tid >> 6;
  const int lane = tid & 63;
  const int quad = lane >> 4;
  const int l16  = lane & 15;
  const int m0   = blockIdx.x * 128 + w * 32;

  f32x4 acc0[NT], acc1[NT];
#pragma unroll
  for (int i = 0; i < NT; ++i) { acc0[i] = (f32x4){0.f,0.f,0.f,0.f}; acc1[i] = (f32x4){0.f,0.f,0.f,0.f}; }

  int r0 = m0 + l16;  int rc0 = (r0 < nN) ? r0 : (nN - 1);
  int r1 = r0 + 16;   int rc1 = (r1 < nN) ? r1 : (nN - 1);
  const size_t abase0 = (size_t)rc0 * 256 + quad * 8;
  const size_t abase1 = (size_t)rc1 * 256 + quad * 8;

  constexpr int CH = (NT * 64) / 256;   // LDS chunks per thread per plane

  for (int kk = 0; kk < 8; ++kk) {
    __syncthreads();
#pragma unroll
    for (int j = 0; j < CH; ++j) {
      int ch = tid + j * 256;
      int nt = ch >> 6; int L = ch & 63;
      int n  = nt * 16 + (L & 15);
      int kb = (L >> 4) * 8;
      *(int4*)(Bh + ch * 8) = *(const int4*)(Wh + n * 256 + kk * 32 + kb);
      *(int4*)(Bl + ch * 8) = *(const int4*)(Wl + n * 256 + kk * 32 + kb);
    }
    __syncthreads();
    bf16x8 ah0, al0, ah1, al1;
    split8(A + abase0 + kk * 32, ah0, al0);
    split8(A + abase1 + kk * 32, ah1, al1);
#pragma unroll
    for (int nt = 0; nt < NT; ++nt) {
      bf16x8 bh = *(const bf16x8*)(Bh + nt * 512 + lane * 8);
      bf16x8 bl = *(const bf16x8*)(Bl + nt * 512 + lane * 8);
      acc0[nt] = __builtin_amdgcn_mfma_f32_16x16x32_bf16(ah0, bh, acc0[nt], 0, 0, 0);
      acc1[nt] = __builtin_amdgcn_mfma_f32_16x16x32_bf16(ah1, bh, acc1[nt], 0, 0, 0);
      acc0[nt] = __builtin_amdgcn_mfma_f32_16x16x32_bf16(al0, bh, acc0[nt], 0, 0, 0);
      acc1[nt] = __builtin_amdgcn_mfma_f32_16x16x32_bf16(al1, bh, acc1[nt], 0, 0, 0);
      acc0[nt] = __builtin_amdgcn_mfma_f32_16x16x32_bf16(ah0, bl, acc0[nt], 0, 0, 0);
      acc1[nt] = __builtin_amdgcn_mfma_f32_16x16x32_bf16(ah1, bl, acc1[nt], 0, 0, 0);
    }
  }

  // epilogue: C/D layout col=lane&15, row=quad*4+reg
  const int N = NT * 16;
#pragma unroll
  for (int reg = 0; reg < 4; ++reg) {
    int rr0 = m0 + quad * 4 + reg;
    int rr1 = rr0 + 16;
    float s0 = 1.f, s1 = 1.f;
    if (SCALE) {
      s0 = snorm[(rr0 < nN) ? rr0 : 0];
      s1 = snorm[(rr1 < nN) ? rr1 : 0];
    }
#pragma unroll
    for (int nt = 0; nt < NT; ++nt) {
      if (rr0 < nN) {
        float v = acc0[nt][reg];
        if (RELU) v = fmaxf(v, 0.f);
        if (SCALE) v *= s0;
        storev(out + (size_t)rr0 * N + nt * 16 + l16, v);
      }
      if (rr1 < nN) {
        float v = acc1[nt][reg];
        if (RELU) v = fmaxf(v, 0.f);
        if (SCALE) v *= s1;
        storev(out + (size_t)rr1 * N + nt * 16 + l16, v);
      }
    }
  }
}

// ---------------- launch ----------------

extern "C" void kernel_launch(void* const* d_in, const int* in_sizes, int n_in,
                              void* d_out, int out_size, void* d_ws, size_t ws_size,
                              hipStream_t stream) {
  const float* feat = (const float*)d_in[0];
  const int*   src  = (const int*)d_in[1];
  const int*   dst  = (const int*)d_in[2];
  const float* W0   = (const float*)d_in[3];
  const float* W1   = (const float*)d_in[4];
  const float* W2   = (const float*)d_in[5];
  const int nE = in_sizes[1];
  const int nN = in_sizes[0] / FEATS;

  char* p = (char*)d_ws;
  auto alloc = [&](size_t bytes) -> void* {
    void* r = (void*)p;
    p += (bytes + 255) & ~(size_t)255;
    return r;
  };
  unsigned* outdeg = (unsigned*)alloc((size_t)nN * 4);
  unsigned* indeg  = (unsigned*)alloc((size_t)nN * 4);
  float*    snorm  = (float*)   alloc((size_t)nN * 4);
  float*    dnorm  = (float*)   alloc((size_t)nN * 4);
  float*    X      = (float*)   alloc((size_t)nN * 256 * 4);  // bf16 X1/F1 live here; fp32 F2 later
  float*    G      = (float*)   alloc((size_t)nN * 256 * 4);  // agg buffer; layer-3 H3 reuses
  unsigned* excl     = (unsigned*)alloc((size_t)nN * 4);
  unsigned* partials = (unsigned*)alloc(1024 * 4);
  unsigned* row_ptr  = (unsigned*)alloc(((size_t)nN + 1) * 4);
  unsigned* cursor   = (unsigned*)alloc((size_t)nN * 4);
  unsigned* edge_src = (unsigned*)alloc((size_t)nE * 4);
  // footprint == proven 220.0 MB

  unsigned short* Xb = (unsigned short*)X;   // bf16 view (uses half the X region)

  // Weight hi/lo planes (576 KB) alias the dead outdeg/indeg region (proven in R9)
  unsigned short* W0h = (unsigned short*)outdeg;
  unsigned short* W0l = W0h + 256 * 256;
  unsigned short* W1h = W0l + 256 * 256;
  unsigned short* W1l = W1h + 256 * 256;
  unsigned short* W2h = W1l + 256 * 256;
  unsigned short* W2l = W2h + 64 * 256;

  hipMemsetAsync(outdeg, 0, (size_t)nN * 4, stream);
  hipMemsetAsync(indeg,  0, (size_t)nN * 4, stream);

  const int TB = 256;
  int gE  = (nE + TB - 1) / TB;
  int gN  = (nN + TB - 1) / TB;
  int nb  = (nN + 1023) / 1024;
  int gRow = (nN * 64 + TB - 1) / TB;   // wave per row/node
  int gGm  = (nN + 127) / 128;          // MFMA gemm: 128 rows/block

  deg_kernel<<<gE, TB, 0, stream>>>(src, dst, outdeg, indeg, nE);
  norm_kernel<<<gN, TB, 0, stream>>>(outdeg, indeg, snorm, dnorm, nN);

  scan_blocks<<<nb, 1024, 0, stream>>>(indeg, excl, partials, nN);
  scan_partials<<<1, 1024, 0, stream>>>(partials, nb);
  finalize_rowptr<<<gN, TB, 0, stream>>>(excl, partials, row_ptr, cursor, nN, nE);
  scatter_kernel<<<gE, TB, 0, stream>>>(src, dst, cursor, edge_src, nE);

  // weight splits into the dead outdeg/indeg region
  cast_w_split<<<(256 * 256 + TB - 1) / TB, TB, 0, stream>>>(W0, W0h, W0l, 256, 256);
  cast_w_split<<<(256 * 256 + TB - 1) / TB, TB, 0, stream>>>(W1, W1h, W1l, 256, 256);
  cast_w_split<<<(256 * 64  + TB - 1) / TB, TB, 0, stream>>>(W2, W2h, W2l, 256, 64);

  int total8 = nN * (FEATS / 8);
  prescale_bf16<<<(total8 + TB - 1) / TB, TB, 0, stream>>>(feat, snorm, Xb, total8);

  // layer 1: G = dn * seg_sum(Xb[src]); F1 = bf16(relu(G @ W0)*sn) -> Xb
  spmm_bf16row<<<gRow, TB, 0, stream>>>(Xb, row_ptr, edge_src, dnorm, G, nN);
  gemm_f32a<16, true, true, unsigned short><<<gGm, TB, 0, stream>>>(G, W0h, W0l, snorm, Xb, nN);
  // layer 2: bf16 gather -> G fp32; F2 = fp32 relu(G @ W1)*sn -> X
  spmm_bf16row<<<gRow, TB, 0, stream>>>(Xb, row_ptr, edge_src, dnorm, G, nN);
  gemm_f32a<16, true, true, float><<<gGm, TB, 0, stream>>>(G, W1h, W1l, snorm, X, nN);
  // layer 3 (all fp32): H3 = X @ W2 -> G; out = dn * seg_sum(H3[src])
  gemm_f32a<4, false, false, float><<<gGm, TB, 0, stream>>>(X, W2h, W2l, nullptr, G, nN);
  spmm64_f32<<<gRow, TB, 0, stream>>>(G, row_ptr, edge_src, dnorm, (float*)d_out, nN);
}

// Round 11
// 1347.341 us; speedup vs baseline: 19.7915x; 1.1504x over previous
//
#include <hip/hip_runtime.h>

// GCN: 3-layer graph conv, N=100000 nodes, E=3.2M edges, feats 256->256->256->64.
// R11 = R10 + (a) atomic-free CSR placement: deg_kernel's indeg atomicAdd return
// value IS the edge's rank in its dst bucket; placement = row_ptr[dst]+rank, plain
// write. (b) layer-3 H3 stored bf16 -> final gather bytes halve.
// Footprint <= proven 220.0 MB (edge_rank aliases dead G space; cursor removed).

typedef __bf16  bf16x8 __attribute__((ext_vector_type(8)));
typedef float   f32x4  __attribute__((ext_vector_type(4)));

#define FEATS 256

static __device__ __forceinline__ unsigned short f2bf(float f) {
  unsigned u = __float_as_uint(f);
  u += 0x7fffu + ((u >> 16) & 1u);          // round-to-nearest-even
  return (unsigned short)(u >> 16);
}
static __device__ __forceinline__ float bfval(unsigned short h) { return __uint_as_float((unsigned)h << 16); }
static __device__ __forceinline__ float bflo(unsigned u) { return __uint_as_float(u << 16); }
static __device__ __forceinline__ float bfhi(unsigned u) { return __uint_as_float(u & 0xffff0000u); }

// ---------------- graph prep ----------------

// degree histograms + per-edge rank within dst bucket (atomic return value)
__global__ void deg_rank_kernel(const int* __restrict__ src, const int* __restrict__ dst,
                                unsigned* __restrict__ outd, unsigned* __restrict__ ind,
                                unsigned* __restrict__ rank, int nE) {
  int i = blockIdx.x * blockDim.x + threadIdx.x;
  if (i < nE) {
    atomicAdd(&outd[src[i]], 1u);
    rank[i] = atomicAdd(&ind[dst[i]], 1u);
  }
}

__global__ void norm_kernel(const unsigned* __restrict__ outd, const unsigned* __restrict__ ind,
                            float* __restrict__ snorm, float* __restrict__ dnorm, int nN) {
  int i = blockIdx.x * blockDim.x + threadIdx.x;
  if (i < nN) {
    unsigned od = outd[i]; if (od < 1u) od = 1u;
    unsigned id = ind[i];  if (id < 1u) id = 1u;
    snorm[i] = 1.0f / sqrtf((float)od);
    dnorm[i] = 1.0f / sqrtf((float)id);
  }
}

// Xb[n][c] = bf16(feat[n][c] * snorm[n]); thread handles 8 elems
__global__ void prescale_bf16(const float* __restrict__ feat, const float* __restrict__ snorm,
                              unsigned short* __restrict__ Xb, int total8 /* nN*32 */) {
  int i8 = blockIdx.x * blockDim.x + threadIdx.x;
  if (i8 >= total8) return;
  float4 u = ((const float4*)feat)[i8 * 2];
  float4 v = ((const float4*)feat)[i8 * 2 + 1];
  float s = snorm[i8 >> 5];
  uint2 a, b;
  a.x = (unsigned)f2bf(u.x * s) | ((unsigned)f2bf(u.y * s) << 16);
  a.y = (unsigned)f2bf(u.z * s) | ((unsigned)f2bf(u.w * s) << 16);
  b.x = (unsigned)f2bf(v.x * s) | ((unsigned)f2bf(v.y * s) << 16);
  b.y = (unsigned)f2bf(v.z * s) | ((unsigned)f2bf(v.w * s) << 16);
  *(uint4*)(Xb + (size_t)i8 * 8) = make_uint4(a.x, a.y, b.x, b.y);
}

// ---------------- CSR build ----------------

__global__ void scan_blocks(const unsigned* __restrict__ in, unsigned* __restrict__ excl,
                            unsigned* __restrict__ partials, int n) {
  __shared__ unsigned tmp[1024];
  int t = threadIdx.x;
  int g = blockIdx.x * 1024 + t;
  unsigned v = (g < n) ? in[g] : 0u;
  tmp[t] = v;
  __syncthreads();
  for (int off = 1; off < 1024; off <<= 1) {
    unsigned add = (t >= off) ? tmp[t - off] : 0u;
    __syncthreads();
    tmp[t] += add;
    __syncthreads();
  }
  if (g < n) excl[g] = tmp[t] - v;
  if (t == 1023) partials[blockIdx.x] = tmp[t];
}

__global__ void scan_partials(unsigned* __restrict__ partials, int nb) {
  __shared__ unsigned tmp[1024];
  int t = threadIdx.x;
  unsigned v = (t < nb) ? partials[t] : 0u;
  tmp[t] = v;
  __syncthreads();
  for (int off = 1; off < 1024; off <<= 1) {
    unsigned add = (t >= off) ? tmp[t - off] : 0u;
    __syncthreads();
    tmp[t] += add;
    __syncthreads();
  }
  if (t < nb) partials[t] = tmp[t] - v;   // exclusive
}

__global__ void finalize_rowptr(const unsigned* __restrict__ excl, const unsigned* __restrict__ partials,
                                unsigned* __restrict__ row_ptr, int n, int nE) {
  int g = blockIdx.x * blockDim.x + threadIdx.x;
  if (g < n) row_ptr[g] = excl[g] + partials[g >> 10];
  if (g == 0) row_ptr[n] = (unsigned)nE;
}

// atomic-free placement: pos = row_ptr[dst] + rank
__global__ void place_kernel(const int* __restrict__ src, const int* __restrict__ dst,
                             const unsigned* __restrict__ rank, const unsigned* __restrict__ row_ptr,
                             unsigned* __restrict__ edge_src, int nE) {
  int i = blockIdx.x * blockDim.x + threadIdx.x;
  if (i < nE) {
    unsigned pos = row_ptr[dst[i]] + rank[i];
    edge_src[pos] = (unsigned)src[i];
  }
}

// ---------------- weight split (hi/lo, transposed) ----------------

__global__ void cast_w_split(const float* __restrict__ W, unsigned short* __restrict__ Wh,
                             unsigned short* __restrict__ Wl, int K, int N) {
  int i = blockIdx.x * blockDim.x + threadIdx.x;
  if (i < K * N) {
    int n = i / K, k = i - n * K;
    float v = W[k * N + n];
    unsigned short h = f2bf(v);
    Wh[i] = h;
    Wl[i] = f2bf(v - bfval(h));
  }
}

// ---------------- SpMM (CSR gather) — PROVEN loop structure ----------------

// bf16 input: G[d][c] = dnorm[d] * sum_{e: dst=d} Xb[src_e][c]; fp32 accum/out
__global__ void spmm_bf16row(const unsigned short* __restrict__ Xb, const unsigned* __restrict__ row_ptr,
                             const unsigned* __restrict__ edge_src, const float* __restrict__ dnorm,
                             float* __restrict__ G, int nN) {
  int wid  = (blockIdx.x * blockDim.x + threadIdx.x) >> 6;
  int lane = threadIdx.x & 63;
  if (wid >= nN) return;
  unsigned start = row_ptr[wid];
  int cnt = (int)(row_ptr[wid + 1] - start);
  float a0 = 0.f, a1 = 0.f, a2 = 0.f, a3 = 0.f;
  int colbase = lane * 4;
  for (int base = 0; base < cnt; base += 64) {
    int m = cnt - base; if (m > 64) m = 64;
    unsigned myidx = (lane < m) ? edge_src[start + base + lane] : 0u;
    int e = 0;
    for (; e + 1 < m; e += 2) {
      unsigned s0 = __shfl(myidx, e);
      unsigned s1 = __shfl(myidx, e + 1);
      uint2 d0 = *(const uint2*)(Xb + (size_t)s0 * FEATS + colbase);
      uint2 d1 = *(const uint2*)(Xb + (size_t)s1 * FEATS + colbase);
      a0 += bflo(d0.x); a1 += bfhi(d0.x); a2 += bflo(d0.y); a3 += bfhi(d0.y);
      a0 += bflo(d1.x); a1 += bfhi(d1.x); a2 += bflo(d1.y); a3 += bfhi(d1.y);
    }
    if (e < m) {
      unsigned s0 = __shfl(myidx, e);
      uint2 d0 = *(const uint2*)(Xb + (size_t)s0 * FEATS + colbase);
      a0 += bflo(d0.x); a1 += bfhi(d0.x); a2 += bflo(d0.y); a3 += bfhi(d0.y);
    }
  }
  float sc = dnorm[wid];
  *(float4*)(G + (size_t)wid * FEATS + colbase) =
      make_float4(a0 * sc, a1 * sc, a2 * sc, a3 * sc);
}

// 64-dim bf16 input: lane = column, all lanes iterate all edges; fp32 accum; fp32 out
__global__ void spmm64_bf16(const unsigned short* __restrict__ Xb, const unsigned* __restrict__ row_ptr,
                            const unsigned* __restrict__ edge_src, const float* __restrict__ dnorm,
                            float* __restrict__ out, int nN) {
  int wid  = (blockIdx.x * blockDim.x + threadIdx.x) >> 6;
  int lane = threadIdx.x & 63;
  if (wid >= nN) return;
  unsigned start = row_ptr[wid];
  int cnt = (int)(row_ptr[wid + 1] - start);
  float a0 = 0.f;
  for (int base = 0; base < cnt; base += 64) {
    int m = cnt - base; if (m > 64) m = 64;
    unsigned myidx = (lane < m) ? edge_src[start + base + lane] : 0u;
    int e = 0;
    for (; e + 1 < m; e += 2) {
      unsigned s0 = __shfl(myidx, e);
      unsigned s1 = __shfl(myidx, e + 1);
      a0 += bfval(Xb[(size_t)s0 * 64 + lane]);
      a0 += bfval(Xb[(size_t)s1 * 64 + lane]);
    }
    if (e < m) {
      unsigned s0 = __shfl(myidx, e);
      a0 += bfval(Xb[(size_t)s0 * 64 + lane]);
    }
  }
  out[(size_t)wid * 64 + lane] = a0 * dnorm[wid];
}

// ---------------- GEMM: MFMA, fp32-A split, W hi/lo split, 3-term ----------------

static __device__ __forceinline__ void split8(const float* __restrict__ p, bf16x8& h, bf16x8& l) {
  float4 u = *(const float4*)p;
  float4 v = *(const float4*)(p + 4);
  float x[8] = {u.x, u.y, u.z, u.w, v.x, v.y, v.z, v.w};
#pragma unroll
  for (int j = 0; j < 8; ++j) {
    __bf16 hh = (__bf16)x[j];
    h[j] = hh;
    l[j] = (__bf16)(x[j] - (float)hh);
  }
}

static __device__ __forceinline__ void storev(unsigned short* p, float v) { *p = f2bf(v); }
static __device__ __forceinline__ void storev(float* p, float v) { *p = v; }

template<int NT, bool RELU, bool SCALE, typename OutT>
__global__ __launch_bounds__(256)
void gemm_f32a(const float* __restrict__ A,
               const unsigned short* __restrict__ Wh, const unsigned short* __restrict__ Wl,
               const float* __restrict__ snorm, OutT* __restrict__ out, int nN) {
  __shared__ unsigned short Bh[NT * 512];   // [nt][lane][8] bf16, frag-linear
  __shared__ unsigned short Bl[NT * 512];
  const int tid  = threadIdx.x;
  const int w    = tid >> 6;
  const int lane = tid & 63;
  const int quad = lane >> 4;
  const int l16  = lane & 15;
  const int m0   = blockIdx.x * 128 + w * 32;

  f32x4 acc0[NT], acc1[NT];
#pragma unroll
  for (int i = 0; i < NT; ++i) { acc0[i] = (f32x4){0.f,0.f,0.f,0.f}; acc1[i] = (f32x4){0.f,0.f,0.f,0.f}; }

  int r0 = m0 + l16;  int rc0 = (r0 < nN) ? r0 : (nN - 1);
  int r1 = r0 + 16;   int rc1 = (r1 < nN) ? r1 : (nN - 1);
  const size_t abase0 = (size_t)rc0 * 256 + quad * 8;
  const size_t abase1 = (size_t)rc1 * 256 + quad * 8;

  constexpr int CH = (NT * 64) / 256;   // LDS chunks per thread per plane

  for (int kk = 0; kk < 8; ++kk) {
    __syncthreads();
#pragma unroll
    for (int j = 0; j < CH; ++j) {
      int ch = tid + j * 256;
      int nt = ch >> 6; int L = ch & 63;
      int n  = nt * 16 + (L & 15);
      int kb = (L >> 4) * 8;
      *(int4*)(Bh + ch * 8) = *(const int4*)(Wh + n * 256 + kk * 32 + kb);
      *(int4*)(Bl + ch * 8) = *(const int4*)(Wl + n * 256 + kk * 32 + kb);
    }
    __syncthreads();
    bf16x8 ah0, al0, ah1, al1;
    split8(A + abase0 + kk * 32, ah0, al0);
    split8(A + abase1 + kk * 32, ah1, al1);
#pragma unroll
    for (int nt = 0; nt < NT; ++nt) {
      bf16x8 bh = *(const bf16x8*)(Bh + nt * 512 + lane * 8);
      bf16x8 bl = *(const bf16x8*)(Bl + nt * 512 + lane * 8);
      acc0[nt] = __builtin_amdgcn_mfma_f32_16x16x32_bf16(ah0, bh, acc0[nt], 0, 0, 0);
      acc1[nt] = __builtin_amdgcn_mfma_f32_16x16x32_bf16(ah1, bh, acc1[nt], 0, 0, 0);
      acc0[nt] = __builtin_amdgcn_mfma_f32_16x16x32_bf16(al0, bh, acc0[nt], 0, 0, 0);
      acc1[nt] = __builtin_amdgcn_mfma_f32_16x16x32_bf16(al1, bh, acc1[nt], 0, 0, 0);
      acc0[nt] = __builtin_amdgcn_mfma_f32_16x16x32_bf16(ah0, bl, acc0[nt], 0, 0, 0);
      acc1[nt] = __builtin_amdgcn_mfma_f32_16x16x32_bf16(ah1, bl, acc1[nt], 0, 0, 0);
    }
  }

  // epilogue: C/D layout col=lane&15, row=quad*4+reg
  const int N = NT * 16;
#pragma unroll
  for (int reg = 0; reg < 4; ++reg) {
    int rr0 = m0 + quad * 4 + reg;
    int rr1 = rr0 + 16;
    float s0 = 1.f, s1 = 1.f;
    if (SCALE) {
      s0 = snorm[(rr0 < nN) ? rr0 : 0];
      s1 = snorm[(rr1 < nN) ? rr1 : 0];
    }
#pragma unroll
    for (int nt = 0; nt < NT; ++nt) {
      if (rr0 < nN) {
        float v = acc0[nt][reg];
        if (RELU) v = fmaxf(v, 0.f);
        if (SCALE) v *= s0;
        storev(out + (size_t)rr0 * N + nt * 16 + l16, v);
      }
      if (rr1 < nN) {
        float v = acc1[nt][reg];
        if (RELU) v = fmaxf(v, 0.f);
        if (SCALE) v *= s1;
        storev(out + (size_t)rr1 * N + nt * 16 + l16, v);
      }
    }
  }
}

// ---------------- launch ----------------

extern "C" void kernel_launch(void* const* d_in, const int* in_sizes, int n_in,
                              void* d_out, int out_size, void* d_ws, size_t ws_size,
                              hipStream_t stream) {
  const float* feat = (const float*)d_in[0];
  const int*   src  = (const int*)d_in[1];
  const int*   dst  = (const int*)d_in[2];
  const float* W0   = (const float*)d_in[3];
  const float* W1   = (const float*)d_in[4];
  const float* W2   = (const float*)d_in[5];
  const int nE = in_sizes[1];
  const int nN = in_sizes[0] / FEATS;

  char* p = (char*)d_ws;
  auto alloc = [&](size_t bytes) -> void* {
    void* r = (void*)p;
    p += (bytes + 255) & ~(size_t)255;
    return r;
  };
  unsigned* outdeg = (unsigned*)alloc((size_t)nN * 4);
  unsigned* indeg  = (unsigned*)alloc((size_t)nN * 4);
  float*    snorm  = (float*)   alloc((size_t)nN * 4);
  float*    dnorm  = (float*)   alloc((size_t)nN * 4);
  float*    X      = (float*)   alloc((size_t)nN * 256 * 4);  // bf16 X1/F1; fp32 F2
  float*    G      = (float*)   alloc((size_t)nN * 256 * 4);  // agg buffer; rank + H3b alias
  unsigned* excl     = (unsigned*)alloc((size_t)nN * 4);
  unsigned* partials = (unsigned*)alloc(1024 * 4);
  unsigned* row_ptr  = (unsigned*)alloc(((size_t)nN + 1) * 4);
  unsigned* edge_src = (unsigned*)alloc((size_t)nE * 4);
  // footprint < proven 220.0 MB (cursor removed)

  unsigned short* Xb  = (unsigned short*)X;   // bf16 view (first half of X region)
  unsigned* edge_rank = (unsigned*)G;         // nE*4 = 12.8MB, dead once spmm layer 1 runs
  unsigned short* H3b = (unsigned short*)G;   // layer-3 bf16 output (12.8MB), alias ok

  // Weight hi/lo planes (576 KB) alias the dead outdeg/indeg region (proven R9/R10)
  unsigned short* W0h = (unsigned short*)outdeg;
  unsigned short* W0l = W0h + 256 * 256;
  unsigned short* W1h = W0l + 256 * 256;
  unsigned short* W1l = W1h + 256 * 256;
  unsigned short* W2h = W1l + 256 * 256;
  unsigned short* W2l = W2h + 64 * 256;

  hipMemsetAsync(outdeg, 0, (size_t)nN * 4, stream);
  hipMemsetAsync(indeg,  0, (size_t)nN * 4, stream);

  const int TB = 256;
  int gE  = (nE + TB - 1) / TB;
  int gN  = (nN + TB - 1) / TB;
  int nb  = (nN + 1023) / 1024;
  int gRow = (nN * 64 + TB - 1) / TB;   // wave per row/node
  int gGm  = (nN + 127) / 128;          // MFMA gemm: 128 rows/block

  deg_rank_kernel<<<gE, TB, 0, stream>>>(src, dst, outdeg, indeg, edge_rank, nE);
  norm_kernel<<<gN, TB, 0, stream>>>(outdeg, indeg, snorm, dnorm, nN);

  scan_blocks<<<nb, 1024, 0, stream>>>(indeg, excl, partials, nN);
  scan_partials<<<1, 1024, 0, stream>>>(partials, nb);
  finalize_rowptr<<<gN, TB, 0, stream>>>(excl, partials, row_ptr, nN, nE);
  place_kernel<<<gE, TB, 0, stream>>>(src, dst, edge_rank, row_ptr, edge_src, nE);

  // weight splits into the dead outdeg/indeg region
  cast_w_split<<<(256 * 256 + TB - 1) / TB, TB, 0, stream>>>(W0, W0h, W0l, 256, 256);
  cast_w_split<<<(256 * 256 + TB - 1) / TB, TB, 0, stream>>>(W1, W1h, W1l, 256, 256);
  cast_w_split<<<(256 * 64  + TB - 1) / TB, TB, 0, stream>>>(W2, W2h, W2l, 256, 64);

  int total8 = nN * (FEATS / 8);
  prescale_bf16<<<(total8 + TB - 1) / TB, TB, 0, stream>>>(feat, snorm, Xb, total8);

  // layer 1: G = dn * seg_sum(Xb[src]); F1 = bf16(relu(G @ W0)*sn) -> Xb
  spmm_bf16row<<<gRow, TB, 0, stream>>>(Xb, row_ptr, edge_src, dnorm, G, nN);
  gemm_f32a<16, true, true, unsigned short><<<gGm, TB, 0, stream>>>(G, W0h, W0l, snorm, Xb, nN);
  // layer 2: bf16 gather -> G fp32; F2 = fp32 relu(G @ W1)*sn -> X
  spmm_bf16row<<<gRow, TB, 0, stream>>>(Xb, row_ptr, edge_src, dnorm, G, nN);
  gemm_f32a<16, true, true, float><<<gGm, TB, 0, stream>>>(G, W1h, W1l, snorm, X, nN);
  // layer 3: H3b = bf16(X @ W2) -> G region; out = dn * seg_sum(H3b[src]) in fp32
  gemm_f32a<4, false, false, unsigned short><<<gGm, TB, 0, stream>>>(X, W2h, W2l, nullptr, H3b, nN);
  spmm64_bf16<<<gRow, TB, 0, stream>>>(H3b, row_ptr, edge_src, dnorm, (float*)d_out, nN);
}